// Round 6
// baseline (370.878 us; speedup 1.0000x reference)
//
#include <hip/hip_runtime.h>

typedef unsigned short u16;
typedef unsigned int u32;
typedef __attribute__((ext_vector_type(8))) short bf16x8;   // 8 bf16 = 4 VGPRs
typedef __attribute__((ext_vector_type(4))) float f32x4;

__device__ __forceinline__ u16 f2bf(float f) {
  u32 u = __float_as_uint(f);
  u += 0x7fffu + ((u >> 16) & 1u);   // RNE
  return (u16)(u >> 16);
}

// ---------------- prep_small: W01 (64KB) and W23 (256KB), both L2-resident ----
__global__ void prep_small(const float* __restrict__ f0, const float* __restrict__ f1,
                           const float* __restrict__ f2, const float* __restrict__ f3,
                           float* __restrict__ W01, float* __restrict__ W23) {
  int b = blockIdx.x;
  if (b < 256) {
    int idx = b * 256 + threadIdx.x;           // 65536 = [o0][o1][i0][i1][r2]
    int r2 = idx & 15; int t = idx >> 4;
    int i1 = t & 7; t >>= 3;
    int i0 = t & 7; t >>= 3;
    int o1 = t & 7; int o0 = t >> 3;
    const float* a = f0 + (o0 * 8 + i0) * 16;          // stride r1 = 1
    const float* c = f1 + (o1 * 8 + i1) * 16 + r2;     // stride r1 = 1024
    float s = 0.f;
#pragma unroll
    for (int r1 = 0; r1 < 16; ++r1) s += a[r1] * c[r1 * 1024];
    W01[idx] = s;
  } else {
    int idx = (b - 256) * 256 + threadIdx.x;   // 65536 = [r2][o2][i2][o3][i3]
    int i3 = idx & 7, o3 = (idx >> 3) & 7, i2 = (idx >> 6) & 7;
    int o2 = (idx >> 9) & 7, r2 = idx >> 12;
    const float* a = f2 + ((r2 * 8 + o2) * 8 + i2) * 16;  // stride r3 = 1
    const float* c = f3 + o3 * 8 + i3;                    // stride r3 = 64
    float s = 0.f;
#pragma unroll
    for (int r3 = 0; r3 < 16; ++r3) s += a[r3] * c[r3 * 64];
    W23[idx] = s;
  }
}

// ---------------- prep_big: cvt x (blocks 0..8191) + build W (blocks 8192..12287)
__global__ void prep_big(const float* __restrict__ W01, const float* __restrict__ W23,
                         const float* __restrict__ x, u16* __restrict__ W,
                         uint4* __restrict__ xb) {
  int b = blockIdx.x;
  if (b < 8192) {
    int idx = b * 256 + threadIdx.x;           // 2,097,152 threads * 8 elems
    float4 a = ((const float4*)x)[idx * 2], d = ((const float4*)x)[idx * 2 + 1];
    union { u16 h[8]; uint4 v; } r;
    r.h[0] = f2bf(a.x); r.h[1] = f2bf(a.y); r.h[2] = f2bf(a.z); r.h[3] = f2bf(a.w);
    r.h[4] = f2bf(d.x); r.h[5] = f2bf(d.y); r.h[6] = f2bf(d.z); r.h[7] = f2bf(d.w);
    xb[idx] = r.v;
    return;
  }
  const int o = b - 8192;                      // 4096 rows
  const int o2 = (o >> 3) & 7, o3 = o & 7;
  const int tid = threadIdx.x;
  __shared__ float sW23[1024];                 // [r2][i2*8+i3]
  {
    int e = tid * 4;
    const float* src = W23 + (e >> 6) * 4096 + o2 * 512 + ((e >> 3) & 7) * 64
                         + o3 * 8 + (e & 7);
    ((float4*)sW23)[tid] = *(const float4*)src;
  }
  float w01r[16];
  {
    const float* a = W01 + (((o >> 6) * 64 + (tid >> 2)) << 4);
#pragma unroll
    for (int q = 0; q < 4; ++q) {
      float4 v = *(const float4*)(a + q * 4);
      w01r[q * 4] = v.x; w01r[q * 4 + 1] = v.y; w01r[q * 4 + 2] = v.z; w01r[q * 4 + 3] = v.w;
    }
  }
  __syncthreads();

  const int i2a = 2 * (tid & 3), i2b = i2a + 1;
  float acc[16] = {};
#pragma unroll
  for (int r2 = 0; r2 < 16; ++r2) {
    const float w = w01r[r2];
    const float4 va0 = *(const float4*)(sW23 + r2 * 64 + i2a * 8);
    const float4 va1 = *(const float4*)(sW23 + r2 * 64 + i2a * 8 + 4);
    const float4 vb0 = *(const float4*)(sW23 + r2 * 64 + i2b * 8);
    const float4 vb1 = *(const float4*)(sW23 + r2 * 64 + i2b * 8 + 4);
    acc[0]  += w * va0.x; acc[1]  += w * va0.y; acc[2]  += w * va0.z; acc[3]  += w * va0.w;
    acc[4]  += w * va1.x; acc[5]  += w * va1.y; acc[6]  += w * va1.z; acc[7]  += w * va1.w;
    acc[8]  += w * vb0.x; acc[9]  += w * vb0.y; acc[10] += w * vb0.z; acc[11] += w * vb0.w;
    acc[12] += w * vb1.x; acc[13] += w * vb1.y; acc[14] += w * vb1.z; acc[15] += w * vb1.w;
  }
  union { u16 h[8]; uint4 v; } r0, r1;
#pragma unroll
  for (int j = 0; j < 8; ++j) { r0.h[j] = f2bf(acc[j]); r1.h[j] = f2bf(acc[8 + j]); }
  uint4* dst = (uint4*)(W + (size_t)o * 4096 + tid * 16);
  dst[0] = r0.v; dst[1] = r1.v;
}

// ------ 256x256 4-wave bf16 GEMM, wave tile 128x128:  C = A * B^T + bias ------
// Rationale: 4 waves (1/SIMD) halve LDS read redundancy (64 b128/tile = 768 cyc
// vs MFMA 1242 cyc) so ds_reads hide under the MFMA shadow.  4-slot BK=32 LDS
// ring, counted vmcnt, 2 raw s_barriers/tile, 4 quadrant phases with fixed
// buffer roles: P0 Q00(a0,b0) pf a1 | P1 Q10(a1,b0) pf b1, publish |
// P2 Q01(a0,b1) pf b0<-next | P3 Q11(a1,b1) pf a0<-next, WAR barrier.
// Swizzle (both sides, rule #21): phys 16B-slot = logical ^ ((row>>1)&3).
__device__ __forceinline__ void gload_lds16(const void* g, void* l) {
  __builtin_amdgcn_global_load_lds((__attribute__((address_space(1))) void*)(g),
                                   (__attribute__((address_space(3))) void*)(l),
                                   16, 0, 0);
}

__global__ __launch_bounds__(256, 1) void gemm256(
    const u16* __restrict__ A, const u16* __restrict__ B,
    const float* __restrict__ bias, float* __restrict__ C) {
  constexpr int K = 4096, N = 4096, NT = 128;
  __shared__ u16 S[65536];              // 4 slots x (A[256][32] | B[256][32])
  const int tid  = threadIdx.x;
  const int wave = tid >> 6, lane = tid & 63;
  const int l15 = lane & 15, l4 = lane >> 4;
  const int wr = wave >> 1, wc = wave & 1;     // 2 x 2 wave grid
  const int bm = (int)(blockIdx.x >> 4) * 256;
  const int bn = (int)(blockIdx.x & 15) * 256;

  // staging: thread covers row rg (within a 64-row group), phys 16B-slot tid&3
  const int rg = tid >> 2;
  const int ls = (tid & 3) ^ ((rg >> 1) & 3);  // pre-swizzled source slot
  const u16* pA0 = A + (size_t)(bm +       rg) * K + ls * 8;
  const u16* pA1 = A + (size_t)(bm +  64 + rg) * K + ls * 8;
  const u16* pA2 = A + (size_t)(bm + 128 + rg) * K + ls * 8;
  const u16* pA3 = A + (size_t)(bm + 192 + rg) * K + ls * 8;
  const u16* pB0 = B + (size_t)(bn +       rg) * K + ls * 8;
  const u16* pB1 = B + (size_t)(bn +  64 + rg) * K + ls * 8;
  const u16* pB2 = B + (size_t)(bn + 128 + rg) * K + ls * 8;
  const u16* pB3 = B + (size_t)(bn + 192 + rg) * K + ls * 8;
  const int dl = tid * 8;                      // u16 units; wave-uniform+lane*16B

  // loop-invariant swizzled read offsets (u16 units within a slot)
  int offA[8], offB[8];
#pragma unroll
  for (int mi = 0; mi < 8; ++mi) {
    int r = wr * 128 + mi * 16 + l15;
    offA[mi] = r * 32 + ((l4 ^ ((r >> 1) & 3)) * 8);
  }
#pragma unroll
  for (int ni = 0; ni < 8; ++ni) {
    int r = wc * 128 + ni * 16 + l15;
    offB[ni] = 8192 + r * 32 + ((l4 ^ ((r >> 1) & 3)) * 8);
  }

#define STG_A01(kts) do { u16* _b = S + ((kts) & 3) * 16384;                     \
    gload_lds16(pA0 + (size_t)(kts) * 32, _b + dl);                              \
    gload_lds16(pA1 + (size_t)(kts) * 32, _b + 2048 + dl); } while (0)
#define STG_A23(kts) do { u16* _b = S + ((kts) & 3) * 16384;                     \
    gload_lds16(pA2 + (size_t)(kts) * 32, _b + 4096 + dl);                       \
    gload_lds16(pA3 + (size_t)(kts) * 32, _b + 6144 + dl); } while (0)
#define STG_B01(kts) do { u16* _b = S + ((kts) & 3) * 16384;                     \
    gload_lds16(pB0 + (size_t)(kts) * 32, _b + 8192 + dl);                       \
    gload_lds16(pB1 + (size_t)(kts) * 32, _b + 10240 + dl); } while (0)
#define STG_B23(kts) do { u16* _b = S + ((kts) & 3) * 16384;                     \
    gload_lds16(pB2 + (size_t)(kts) * 32, _b + 12288 + dl);                      \
    gload_lds16(pB3 + (size_t)(kts) * 32, _b + 14336 + dl); } while (0)
#define STAGE_ALL(kts) do { STG_A01(kts); STG_A23(kts); STG_B01(kts); STG_B23(kts); } while (0)

  // prologue: stage tiles 0,1,2 (24 loads), publish tile 0, preload a0/b0
  STAGE_ALL(0); STAGE_ALL(1); STAGE_ALL(2);
  asm volatile("s_waitcnt vmcnt(16)" ::: "memory");    // tile 0 landed
  __builtin_amdgcn_sched_barrier(0);
  __builtin_amdgcn_s_barrier();

  f32x4 acc[8][8] = {};
  bf16x8 a0[4], a1[4], b0[4], b1[4];
#pragma unroll
  for (int i = 0; i < 4; ++i) a0[i] = *(const bf16x8*)(S + offA[i]);
#pragma unroll
  for (int i = 0; i < 4; ++i) b0[i] = *(const bf16x8*)(S + offB[i]);

  for (int kt = 0; kt < NT; ++kt) {
    const u16* base  = S + (kt & 3) * 16384;
    const u16* baseN = S + ((kt + 1) & 3) * 16384;
    const int kn = (kt + 3) & (NT - 1);   // wrap re-stages same bytes, never read

    // P0: Q00 = a0 x b0 ; prefetch a1 (this tile mi4-7)
#pragma unroll
    for (int i = 0; i < 4; ++i) a1[i] = *(const bf16x8*)(base + offA[4 + i]);
    STG_A01(kn);
#pragma unroll
    for (int mi = 0; mi < 4; ++mi)
#pragma unroll
      for (int ni = 0; ni < 4; ++ni)
        acc[mi][ni] = __builtin_amdgcn_mfma_f32_16x16x32_bf16(
            a0[mi], b0[ni], acc[mi][ni], 0, 0, 0);

    // P1: Q10 = a1 x b0 ; prefetch b1 (this tile ni4-7) ; publish tile kt+1
#pragma unroll
    for (int i = 0; i < 4; ++i) b1[i] = *(const bf16x8*)(base + offB[4 + i]);
    STG_A23(kn);
#pragma unroll
    for (int mi = 0; mi < 4; ++mi)
#pragma unroll
      for (int ni = 0; ni < 4; ++ni)
        acc[4 + mi][ni] = __builtin_amdgcn_mfma_f32_16x16x32_bf16(
            a1[mi], b0[ni], acc[4 + mi][ni], 0, 0, 0);
    asm volatile("s_waitcnt vmcnt(12)" ::: "memory");  // tile kt+1's 8 loads done
    __builtin_amdgcn_sched_barrier(0);
    __builtin_amdgcn_s_barrier();                      // publish tile kt+1

    // P2: Q01 = a0 x b1 ; prefetch b0 <- tile kt+1 ni0-3
#pragma unroll
    for (int i = 0; i < 4; ++i) b0[i] = *(const bf16x8*)(baseN + offB[i]);
    STG_B01(kn);
#pragma unroll
    for (int mi = 0; mi < 4; ++mi)
#pragma unroll
      for (int ni = 0; ni < 4; ++ni)
        acc[mi][4 + ni] = __builtin_amdgcn_mfma_f32_16x16x32_bf16(
            a0[mi], b1[ni], acc[mi][4 + ni], 0, 0, 0);

    // P3: Q11 = a1 x b1 ; prefetch a0 <- tile kt+1 mi0-3 ; WAR barrier
#pragma unroll
    for (int i = 0; i < 4; ++i) a0[i] = *(const bf16x8*)(baseN + offA[i]);
    STG_B23(kn);
#pragma unroll
    for (int mi = 0; mi < 4; ++mi)
#pragma unroll
      for (int ni = 0; ni < 4; ++ni)
        acc[4 + mi][4 + ni] = __builtin_amdgcn_mfma_f32_16x16x32_bf16(
            a1[mi], b1[ni], acc[4 + mi][4 + ni], 0, 0, 0);
    __builtin_amdgcn_s_barrier();                      // all reads of kt done
  }

  // epilogue: C row = (lane>>4)*4 + j (M side), col = lane&15 (N side)
#pragma unroll
  for (int ni = 0; ni < 8; ++ni) {
    const int col = bn + wc * 128 + ni * 16 + l15;
    const float bvs = bias[col];
#pragma unroll
    for (int mi = 0; mi < 8; ++mi) {
      const int row0 = bm + wr * 128 + mi * 16 + l4 * 4;
#pragma unroll
      for (int j = 0; j < 4; ++j)
        C[(size_t)(row0 + j) * N + col] = acc[mi][ni][j] + bvs;
    }
  }
  // drain pending global_load_lds AFTER the epilogue (LDS may be reassigned)
  asm volatile("s_waitcnt vmcnt(0)" ::: "memory");
#undef STG_A01
#undef STG_A23
#undef STG_B01
#undef STG_B23
#undef STAGE_ALL
}

// ---------------- launch ----------------
// d_ws: [0,32M) W bf16 ; [32M,64M) xb bf16
// d_out scratch (overwritten by gemm): [0,256KB) W01 f32 ; [256KB,1.25MB) W23 f32
extern "C" void kernel_launch(void* const* d_in, const int* in_sizes, int n_in,
                              void* d_out, int out_size, void* d_ws, size_t ws_size,
                              hipStream_t stream) {
  const float* x    = (const float*)d_in[0];
  const float* f0   = (const float*)d_in[1];
  const float* f1   = (const float*)d_in[2];
  const float* f2   = (const float*)d_in[3];
  const float* f3   = (const float*)d_in[4];
  const float* bias = (const float*)d_in[5];

  char* ws = (char*)d_ws;
  u16* Wb = (u16*)(ws);
  u16* xb = (u16*)(ws + 33554432);
  float* W01 = (float*)d_out;                 // d_out as temp; gemm overwrites all
  float* W23 = (float*)d_out + 65536;

  prep_small<<<512,   256, 0, stream>>>(f0, f1, f2, f3, W01, W23);
  prep_big  <<<12288, 256, 0, stream>>>(W01, W23, x, Wb, (uint4*)xb);
  gemm256   <<<256,   256, 0, stream>>>(xb, Wb, bias, (float*)d_out);
}

// Round 7
// 152.747 us; speedup vs baseline: 2.4281x; 2.4281x over previous
//
#include <hip/hip_runtime.h>

typedef unsigned short u16;
typedef unsigned int u32;
typedef __attribute__((ext_vector_type(8))) short bf16x8;   // 8 bf16 = 4 VGPRs
typedef __attribute__((ext_vector_type(4))) float f32x4;

__device__ __forceinline__ u16 f2bf(float f) {
  u32 u = __float_as_uint(f);
  u += 0x7fffu + ((u >> 16) & 1u);   // RNE
  return (u16)(u >> 16);
}

// ---------------- prep_small: W01 (64KB) and W23 (256KB), both L2-resident ----
__global__ void prep_small(const float* __restrict__ f0, const float* __restrict__ f1,
                           const float* __restrict__ f2, const float* __restrict__ f3,
                           float* __restrict__ W01, float* __restrict__ W23) {
  int b = blockIdx.x;
  if (b < 256) {
    int idx = b * 256 + threadIdx.x;           // 65536 = [o0][o1][i0][i1][r2]
    int r2 = idx & 15; int t = idx >> 4;
    int i1 = t & 7; t >>= 3;
    int i0 = t & 7; t >>= 3;
    int o1 = t & 7; int o0 = t >> 3;
    const float* a = f0 + (o0 * 8 + i0) * 16;          // stride r1 = 1
    const float* c = f1 + (o1 * 8 + i1) * 16 + r2;     // stride r1 = 1024
    float s = 0.f;
#pragma unroll
    for (int r1 = 0; r1 < 16; ++r1) s += a[r1] * c[r1 * 1024];
    W01[idx] = s;
  } else {
    int idx = (b - 256) * 256 + threadIdx.x;   // 65536 = [r2][o2][i2][o3][i3]
    int i3 = idx & 7, o3 = (idx >> 3) & 7, i2 = (idx >> 6) & 7;
    int o2 = (idx >> 9) & 7, r2 = idx >> 12;
    const float* a = f2 + ((r2 * 8 + o2) * 8 + i2) * 16;  // stride r3 = 1
    const float* c = f3 + o3 * 8 + i3;                    // stride r3 = 64
    float s = 0.f;
#pragma unroll
    for (int r3 = 0; r3 < 16; ++r3) s += a[r3] * c[r3 * 64];
    W23[idx] = s;
  }
}

// ---------------- prep_big: cvt x (blocks 0..8191) + build W (blocks 8192..12287)
__global__ void prep_big(const float* __restrict__ W01, const float* __restrict__ W23,
                         const float* __restrict__ x, u16* __restrict__ W,
                         uint4* __restrict__ xb) {
  int b = blockIdx.x;
  if (b < 8192) {
    int idx = b * 256 + threadIdx.x;           // 2,097,152 threads * 8 elems
    float4 a = ((const float4*)x)[idx * 2], d = ((const float4*)x)[idx * 2 + 1];
    union { u16 h[8]; uint4 v; } r;
    r.h[0] = f2bf(a.x); r.h[1] = f2bf(a.y); r.h[2] = f2bf(a.z); r.h[3] = f2bf(a.w);
    r.h[4] = f2bf(d.x); r.h[5] = f2bf(d.y); r.h[6] = f2bf(d.z); r.h[7] = f2bf(d.w);
    xb[idx] = r.v;
    return;
  }
  const int o = b - 8192;                      // 4096 rows
  const int o2 = (o >> 3) & 7, o3 = o & 7;
  const int tid = threadIdx.x;
  __shared__ float sW23[1024];                 // [r2][i2*8+i3]
  {
    int e = tid * 4;
    const float* src = W23 + (e >> 6) * 4096 + o2 * 512 + ((e >> 3) & 7) * 64
                         + o3 * 8 + (e & 7);
    ((float4*)sW23)[tid] = *(const float4*)src;
  }
  float w01r[16];
  {
    const float* a = W01 + (((o >> 6) * 64 + (tid >> 2)) << 4);
#pragma unroll
    for (int q = 0; q < 4; ++q) {
      float4 v = *(const float4*)(a + q * 4);
      w01r[q * 4] = v.x; w01r[q * 4 + 1] = v.y; w01r[q * 4 + 2] = v.z; w01r[q * 4 + 3] = v.w;
    }
  }
  __syncthreads();

  const int i2a = 2 * (tid & 3), i2b = i2a + 1;
  float acc[16] = {};
#pragma unroll
  for (int r2 = 0; r2 < 16; ++r2) {
    const float w = w01r[r2];
    const float4 va0 = *(const float4*)(sW23 + r2 * 64 + i2a * 8);
    const float4 va1 = *(const float4*)(sW23 + r2 * 64 + i2a * 8 + 4);
    const float4 vb0 = *(const float4*)(sW23 + r2 * 64 + i2b * 8);
    const float4 vb1 = *(const float4*)(sW23 + r2 * 64 + i2b * 8 + 4);
    acc[0]  += w * va0.x; acc[1]  += w * va0.y; acc[2]  += w * va0.z; acc[3]  += w * va0.w;
    acc[4]  += w * va1.x; acc[5]  += w * va1.y; acc[6]  += w * va1.z; acc[7]  += w * va1.w;
    acc[8]  += w * vb0.x; acc[9]  += w * vb0.y; acc[10] += w * vb0.z; acc[11] += w * vb0.w;
    acc[12] += w * vb1.x; acc[13] += w * vb1.y; acc[14] += w * vb1.z; acc[15] += w * vb1.w;
  }
  union { u16 h[8]; uint4 v; } r0, r1;
#pragma unroll
  for (int j = 0; j < 8; ++j) { r0.h[j] = f2bf(acc[j]); r1.h[j] = f2bf(acc[8 + j]); }
  uint4* dst = (uint4*)(W + (size_t)o * 4096 + tid * 16);
  dst[0] = r0.v; dst[1] = r1.v;
}

// ------ 256x256 8-wave bf16 GEMM, role-staggered ping-pong:  C = A*B^T + bias -
// Wave groups L (wr=0) / H (wr=1) run the same 4-slot schedule shifted by one
// slot, so in EVERY barrier slot 4 waves issue ds_reads while the other 4 run
// their 16-MFMA cluster -> LDS pipe (96 b128/tile = 1152 cyc) hides under the
// MFMA pipe (1242 cyc) instead of serializing (round-5: 2347 cyc/tile).
//   L: slot0 R(u0,kt) | slot1 M(u0,kt) | slot2 R(u1,kt) | slot3 M(u1,kt)
//   H: slot0 M(u1,kt-1)| slot1 R(u0,kt) | slot2 M(u0,kt) | slot3 R(u1,kt)
// u0-read = av0(mi0-3)+bv(ni0-3) [8 reads]; u1-read = av1(mi4-7) [4 reads].
// 4-slot LDS ring (BK=32), counted vmcnt(8), 4 raw s_barriers/tile (outside
// the wave-uniform branches), setprio(1) around MFMA clusters (T5: role-split
// present).  Ring invariants identical to round-5: stage kt+3 overwrites tile
// kt-1, whose reads were issued >=1 barrier + global-latency earlier.
// Swizzle (both sides, rule #21): phys 16B-slot = logical ^ ((row>>1)&3).
__device__ __forceinline__ void gload_lds16(const void* g, void* l) {
  __builtin_amdgcn_global_load_lds((__attribute__((address_space(1))) void*)(g),
                                   (__attribute__((address_space(3))) void*)(l),
                                   16, 0, 0);
}

__global__ __launch_bounds__(512, 2) void gemm256(
    const u16* __restrict__ A, const u16* __restrict__ B,
    const float* __restrict__ bias, float* __restrict__ C) {
  constexpr int K = 4096, N = 4096, NT = 128;
  __shared__ u16 S[65536];                    // [slot4][A 8192 | B 8192]  128 KiB
  const int tid  = threadIdx.x;
  const int wave = tid >> 6, lane = tid & 63;
  const int l15 = lane & 15, l4 = lane >> 4;
  const int wr = wave >> 2, wc = wave & 3;    // 2 x 4 wave grid; group = wr
  const bool isL = (wr == 0);
  const int bm = (int)(blockIdx.x >> 4) * 256;
  const int bn = (int)(blockIdx.x & 15) * 256;

  // staging: thread covers row rl (of a 128-row half), phys 16B-slot tid&3
  const int rl = tid >> 2;
  const int ls = (tid & 3) ^ ((rl >> 1) & 3);          // pre-swizzled source slot
  const u16* srcA0 = A + (size_t)(bm +       rl) * K + ls * 8;
  const u16* srcA1 = A + (size_t)(bm + 128 + rl) * K + ls * 8;
  const u16* srcB0 = B + (size_t)(bn +       rl) * K + ls * 8;
  const u16* srcB1 = B + (size_t)(bn + 128 + rl) * K + ls * 8;
  const int dA0 = wave * 512,         dA1 = 4096  + wave * 512;   // wave-uniform
  const int dB0 = 8192 + wave * 512,  dB1 = 12288 + wave * 512;   // LDS dest (u16)

  // loop-invariant swizzled read offsets (u16 units within a slot)
  int offA[8], offB[4];
#pragma unroll
  for (int mi = 0; mi < 8; ++mi) {
    int r = wr * 128 + mi * 16 + l15;
    offA[mi] = r * 32 + ((l4 ^ ((r >> 1) & 3)) * 8);
  }
#pragma unroll
  for (int ni = 0; ni < 4; ++ni) {
    int r = wc * 64 + ni * 16 + l15;
    offB[ni] = 8192 + r * 32 + ((l4 ^ ((r >> 1) & 3)) * 8);
  }

#define STAGE_A(kts) do { int _s = (kts) & 3; u16* _b = S + _s * 16384;          \
    gload_lds16(srcA0 + (size_t)(kts) * 32, _b + dA0);                           \
    gload_lds16(srcA1 + (size_t)(kts) * 32, _b + dA1); } while (0)
#define STAGE_B(kts) do { int _s = (kts) & 3; u16* _b = S + _s * 16384;          \
    gload_lds16(srcB0 + (size_t)(kts) * 32, _b + dB0);                           \
    gload_lds16(srcB1 + (size_t)(kts) * 32, _b + dB1); } while (0)

#define READ_U0(base_) do {                                                      \
    _Pragma("unroll")                                                            \
    for (int i = 0; i < 4; ++i) av0[i] = *(const bf16x8*)((base_) + offA[i]);    \
    _Pragma("unroll")                                                            \
    for (int i = 0; i < 4; ++i) bv[i]  = *(const bf16x8*)((base_) + offB[i]);    \
  } while (0)
#define READ_U1(base_) do {                                                      \
    _Pragma("unroll")                                                            \
    for (int i = 0; i < 4; ++i) av1[i] = *(const bf16x8*)((base_) + offA[4 + i]);\
  } while (0)
#define MFMA_U0() do {                                                           \
    __builtin_amdgcn_s_setprio(1);                                               \
    _Pragma("unroll")                                                            \
    for (int mi = 0; mi < 4; ++mi)                                               \
      _Pragma("unroll")                                                          \
      for (int ni = 0; ni < 4; ++ni)                                             \
        acc[mi][ni] = __builtin_amdgcn_mfma_f32_16x16x32_bf16(                   \
            av0[mi], bv[ni], acc[mi][ni], 0, 0, 0);                              \
    __builtin_amdgcn_s_setprio(0);                                               \
  } while (0)
#define MFMA_U1() do {                                                           \
    __builtin_amdgcn_s_setprio(1);                                               \
    _Pragma("unroll")                                                            \
    for (int mi = 0; mi < 4; ++mi)                                               \
      _Pragma("unroll")                                                          \
      for (int ni = 0; ni < 4; ++ni)                                             \
        acc[4 + mi][ni] = __builtin_amdgcn_mfma_f32_16x16x32_bf16(               \
            av1[mi], bv[ni], acc[4 + mi][ni], 0, 0, 0);                          \
    __builtin_amdgcn_s_setprio(0);                                               \
  } while (0)

  // prologue: stage tiles 0,1,2 (12 in flight), publish tile 0
  STAGE_A(0); STAGE_B(0);
  STAGE_A(1); STAGE_B(1);
  STAGE_A(2); STAGE_B(2);
  asm volatile("s_waitcnt vmcnt(8)" ::: "memory");     // tile 0 landed
  __builtin_amdgcn_sched_barrier(0);
  __builtin_amdgcn_s_barrier();

  f32x4 acc[8][4] = {};
  bf16x8 av0[4], av1[4], bv[4];

  for (int kt = 0; kt < NT; ++kt) {
    const u16* base = S + (kt & 3) * 16384;
    const int kn = (kt + 3) & (NT - 1);     // wrap re-stages same bytes, never read

    // ---- slot0: L reads u0(kt) | H mfmas u1(kt-1) ----
    if (isL)          READ_U0(base);
    else if (kt > 0)  MFMA_U1();
    STAGE_A(kn);
    __builtin_amdgcn_s_barrier();

    // ---- slot1: L mfmas u0(kt) | H reads u0(kt) ----
    if (isL)  MFMA_U0();
    else      READ_U0(base);
    __builtin_amdgcn_s_barrier();

    // ---- slot2: L reads u1(kt) | H mfmas u0(kt) ----
    if (isL)  READ_U1(base);
    else      MFMA_U0();
    STAGE_B(kn);
    __builtin_amdgcn_s_barrier();

    // ---- slot3: L mfmas u1(kt) | H reads u1(kt) ; publish tile kt+1 ----
    if (isL)  MFMA_U1();
    else      READ_U1(base);
    asm volatile("s_waitcnt vmcnt(8)" ::: "memory");   // tile kt+1's 4 loads done
    __builtin_amdgcn_sched_barrier(0);
    __builtin_amdgcn_s_barrier();
  }
  // H still owes its last MFMA cluster (u1 of tile NT-1)
  if (!isL) MFMA_U1();

  // epilogue: C row = (lane>>4)*4 + j (M side), col = lane&15 (N side)
#pragma unroll
  for (int ni = 0; ni < 4; ++ni) {
    const int col = bn + wc * 64 + ni * 16 + l15;
    const float bvs = bias[col];
#pragma unroll
    for (int mi = 0; mi < 8; ++mi) {
      const int row0 = bm + wr * 128 + mi * 16 + l4 * 4;
#pragma unroll
      for (int j = 0; j < 4; ++j)
        C[(size_t)(row0 + j) * N + col] = acc[mi][ni][j] + bvs;
    }
  }
  // drain pending global_load_lds AFTER the epilogue (LDS may be reassigned)
  asm volatile("s_waitcnt vmcnt(0)" ::: "memory");
#undef STAGE_A
#undef STAGE_B
#undef READ_U0
#undef READ_U1
#undef MFMA_U0
#undef MFMA_U1
}

// ---------------- launch ----------------
// d_ws: [0,32M) W bf16 ; [32M,64M) xb bf16
// d_out scratch (overwritten by gemm): [0,256KB) W01 f32 ; [256KB,1.25MB) W23 f32
extern "C" void kernel_launch(void* const* d_in, const int* in_sizes, int n_in,
                              void* d_out, int out_size, void* d_ws, size_t ws_size,
                              hipStream_t stream) {
  const float* x    = (const float*)d_in[0];
  const float* f0   = (const float*)d_in[1];
  const float* f1   = (const float*)d_in[2];
  const float* f2   = (const float*)d_in[3];
  const float* f3   = (const float*)d_in[4];
  const float* bias = (const float*)d_in[5];

  char* ws = (char*)d_ws;
  u16* Wb = (u16*)(ws);
  u16* xb = (u16*)(ws + 33554432);
  float* W01 = (float*)d_out;                 // d_out as temp; gemm overwrites all
  float* W23 = (float*)d_out + 65536;

  prep_small<<<512,   256, 0, stream>>>(f0, f1, f2, f3, W01, W23);
  prep_big  <<<12288, 256, 0, stream>>>(W01, W23, x, Wb, (uint4*)xb);
  gemm256   <<<256,   512, 0, stream>>>(xb, Wb, bias, (float*)d_out);
}